// Round 5
// baseline (659.943 us; speedup 1.0000x reference)
//
#include <hip/hip_runtime.h>
#include <hip/hip_bf16.h>

#define NPTS 50000
#define CIN  512
#define PCH  128
#define KNB  27
#define EPSV 1e-5f
#define NEGS 0.1f

typedef __bf16 bf16;
typedef __bf16 bf16x8 __attribute__((ext_vector_type(8)));
typedef __bf16 bf16x4 __attribute__((ext_vector_type(4)));
typedef float  f32x4  __attribute__((ext_vector_type(4)));

// ---- async global->LDS (16B per lane). LDS dest = wave-uniform base + lane*16. ----
typedef void __attribute__((address_space(3)))* as3ptr;
typedef const void __attribute__((address_space(1)))* as1ptr;
__device__ __forceinline__ void gl_lds16(const void* g, void* l) {
  __builtin_amdgcn_global_load_lds((as1ptr)g, (as3ptr)l, 16, 0, 0);
}

// ---------------- x -> bf16 (for global_load_lds staging in gemm1) ----------------
__global__ void xcvt_kernel(const float* __restrict__ x, bf16* __restrict__ xb) {
  int i = (blockIdx.x * blockDim.x + threadIdx.x) * 8;
  if (i >= NPTS * CIN) return;
  float4 a = *(const float4*)&x[i];
  float4 b = *(const float4*)&x[i + 4];
  bf16x8 o;
  o[0] = (bf16)a.x; o[1] = (bf16)a.y; o[2] = (bf16)a.z; o[3] = (bf16)a.w;
  o[4] = (bf16)b.x; o[5] = (bf16)b.y; o[6] = (bf16)b.z; o[7] = (bf16)b.w;
  *(bf16x8*)&xb[i] = o;
}

// ---------------- generic weight transpose+cvt: dst[C][R] = src[R][C] ----
__global__ void tcvt_kernel(const float* __restrict__ src, bf16* __restrict__ dst,
                            int R, int Ccols) {
  int i = blockIdx.x * blockDim.x + threadIdx.x;
  if (i >= R * Ccols) return;
  int c = i / R, r = i - c * R;
  dst[i] = (bf16)src[(size_t)r * Ccols + c];
}

// ---------------- W2 [k][c][d] -> w2k [k][d][c] (bf16) ----------------
__global__ void tcvt_w2k_kernel(const float* __restrict__ src, bf16* __restrict__ dst) {
  int i = blockIdx.x * blockDim.x + threadIdx.x;
  if (i >= KNB * PCH * PCH) return;
  int k = i >> 14, rem = i & 16383;
  int d = rem >> 7, c = rem & 127;
  dst[i] = (bf16)src[(k << 14) + c * 128 + d];
}

// ---------------- prep: nbrT + coverage ratio + valid2 ----------------
__global__ void prep_kernel(const int* __restrict__ nbr, const float* __restrict__ mask,
                            int* __restrict__ nbrT, float* __restrict__ ratio,
                            float* __restrict__ valid2) {
  int n = blockIdx.x * blockDim.x + threadIdx.x;
  if (n >= NPTS) return;
  float s = 0.f;
#pragma unroll
  for (int k = 0; k < KNB; ++k) {
    int idx = nbr[n * KNB + k];
    nbrT[k * NPTS + n] = idx;
    s += (mask[idx] > 0.f) ? 1.f : 0.f;
  }
  ratio[n]  = s > 0.f ? 27.0f / s : 0.f;
  valid2[n] = s > 0.f ? 1.f : 0.f;
}

__global__ void finalize_kernel(const float* __restrict__ ssum, const float* __restrict__ ssq,
                                float* __restrict__ mu, float* __restrict__ inv) {
  int c = threadIdx.x;
  float m = ssum[c] / (float)NPTS;
  float v = ssq[c] / (float)NPTS - m * m;
  mu[c]  = m;
  inv[c] = rsqrtf(v + EPSV);
}

// ---------------- normalize + lrelu + row-mask -> bf16 (C = 128) ----------------
__global__ void ew_kernel(const float* __restrict__ in, const float* __restrict__ mu,
                          const float* __restrict__ inv, const float* __restrict__ rowmask,
                          bf16* __restrict__ outb) {
  int i = (blockIdx.x * blockDim.x + threadIdx.x) * 4;
  if (i >= NPTS * PCH) return;
  float4 v = *(const float4*)&in[i];
  int c = i & 127;
  int row = i >> 7;
  float mk = rowmask[row];
  float t0 = (v.x - mu[c + 0]) * inv[c + 0];
  float t1 = (v.y - mu[c + 1]) * inv[c + 1];
  float t2 = (v.z - mu[c + 2]) * inv[c + 2];
  float t3 = (v.w - mu[c + 3]) * inv[c + 3];
  t0 = (t0 >= 0.f ? t0 : NEGS * t0) * mk;
  t1 = (t1 >= 0.f ? t1 : NEGS * t1) * mk;
  t2 = (t2 >= 0.f ? t2 : NEGS * t2) * mk;
  t3 = (t3 >= 0.f ? t3 : NEGS * t3) * mk;
  bf16x4 o;
  o[0] = (bf16)t0; o[1] = (bf16)t1; o[2] = (bf16)t2; o[3] = (bf16)t3;
  *(bf16x4*)&outb[i] = o;
}

// ---------------- final: out = lrelu(inorm(out3n) + x), out3n bf16 ----------------
__global__ void final_kernel(const float* __restrict__ x, const bf16* __restrict__ out3n,
                             const float* __restrict__ mu, const float* __restrict__ inv,
                             float* __restrict__ out) {
  int i = (blockIdx.x * blockDim.x + threadIdx.x) * 8;
  if (i >= NPTS * CIN) return;
  bf16x8 v = *(const bf16x8*)&out3n[i];
  float4 x0 = *(const float4*)&x[i];
  float4 x1 = *(const float4*)&x[i + 4];
  int c = i & 511;
  float t[8];
  float xv[8] = {x0.x, x0.y, x0.z, x0.w, x1.x, x1.y, x1.z, x1.w};
#pragma unroll
  for (int q = 0; q < 8; ++q) {
    float u = ((float)v[q] - mu[c + q]) * inv[c + q] + xv[q];
    t[q] = u >= 0.f ? u : NEGS * u;
  }
  float4 o0 = {t[0], t[1], t[2], t[3]}, o1 = {t[4], t[5], t[6], t[7]};
  *(float4*)&out[i] = o0;
  *(float4*)&out[i + 4] = o1;
}

__global__ void maskout_kernel(const float* __restrict__ mask, const float* __restrict__ valid2,
                               float* __restrict__ outm) {
  int n = blockIdx.x * blockDim.x + threadIdx.x;
  if (n >= NPTS) return;
  outm[n] = fminf(valid2[n] + mask[n], 1.f);
}

// =================== GEMM kernels ===================
// MFMA 16x16x32 bf16. A frag: lane holds A[m=lane&15][k=(lane>>4)*8+j].
// B frag: lane holds B^T[n=lane&15][k=(lane>>4)*8+j]. C/D: col=lane&15, row=(lane>>4)*4+reg.

// GEMM1 (round-3 structure): LDS staging via global_load_lds, chunk-XOR swizzle,
// B-first VMEM order, pipelined over 4 K-tiles.
__global__ __launch_bounds__(256) void gemm1_kernel(
    const bf16* __restrict__ xb, const bf16* __restrict__ w1t,
    const float* __restrict__ mask, float* __restrict__ out1,
    float* __restrict__ ssum, float* __restrict__ ssq) {
  __shared__ __align__(16) bf16 As[2][128 * 128];
  int row0 = blockIdx.x * 128;
  int tid = threadIdx.x;
  int lane = tid & 63, wid = tid >> 6;
  int mq = (wid >> 1) * 64, nq = (wid & 1) * 64;
  int lr = lane & 15, lq = lane >> 4;
  int rb = tid >> 4;
  int msw = (tid & 15) ^ (rb & 7);
  int rowc[8];
#pragma unroll
  for (int j = 0; j < 8; ++j) {
    int rr = row0 + rb + 16 * j;
    rowc[j] = rr < NPTS ? rr : NPTS - 1;  // clamp: garbage rows never stored
  }
  f32x4 acc[4][4];
#pragma unroll
  for (int i = 0; i < 4; ++i)
#pragma unroll
    for (int j = 0; j < 4; ++j)
#pragma unroll
      for (int r = 0; r < 4; ++r) acc[i][j][r] = 0.f;

#pragma unroll
  for (int j = 0; j < 8; ++j)
    gl_lds16(xb + (size_t)rowc[j] * CIN + (msw << 3),
             &As[0][(j * 256 + wid * 64) * 8]);
  __syncthreads();

  for (int kc = 0; kc < 4; ++kc) {
    int cur = kc & 1;
    const bf16* bp = w1t + (size_t)(nq + lr) * CIN + kc * 128 + lq * 8;
    bf16x8 bfg[4][4];
#pragma unroll
    for (int c0i = 0; c0i < 4; ++c0i)
#pragma unroll
      for (int i = 0; i < 4; ++i)
        bfg[c0i][i] = *(const bf16x8*)(bp + (size_t)i * 16 * CIN + c0i * 32);
    if (kc < 3) {
#pragma unroll
      for (int j = 0; j < 8; ++j)
        gl_lds16(xb + (size_t)rowc[j] * CIN + (kc + 1) * 128 + (msw << 3),
                 &As[cur ^ 1][(j * 256 + wid * 64) * 8]);
    }
#pragma unroll
    for (int c0i = 0; c0i < 4; ++c0i) {
      int cs = ((c0i << 2) + lq) ^ (lr & 7);
      bf16x8 af[4];
#pragma unroll
      for (int i = 0; i < 4; ++i) af[i] = *(const bf16x8*)&As[cur][(mq + i * 16 + lr) * 128 + cs * 8];
#pragma unroll
      for (int i = 0; i < 4; ++i)
#pragma unroll
        for (int j = 0; j < 4; ++j)
          acc[i][j] = __builtin_amdgcn_mfma_f32_16x16x32_bf16(af[i], bfg[c0i][j], acc[i][j], 0, 0, 0);
    }
    __syncthreads();
  }
  float rs[4][4];
#pragma unroll
  for (int i = 0; i < 4; ++i)
#pragma unroll
    for (int r = 0; r < 4; ++r) {
      int row = row0 + mq + i * 16 + lq * 4 + r;
      rs[i][r] = (row < NPTS) ? (mask[row] > 0.f ? 1.f : 0.f) : 0.f;
    }
#pragma unroll
  for (int j = 0; j < 4; ++j) {
    int col = nq + j * 16 + lr;
    float s = 0.f, q = 0.f;
#pragma unroll
    for (int i = 0; i < 4; ++i) {
#pragma unroll
      for (int r = 0; r < 4; ++r) {
        int row = row0 + mq + i * 16 + lq * 4 + r;
        if (row < NPTS) {
          float v = acc[i][j][r] * rs[i][r];
          out1[(size_t)row * PCH + col] = v;
          s += v; q += v * v;
        }
      }
    }
    s += __shfl_xor(s, 16); s += __shfl_xor(s, 32);
    q += __shfl_xor(q, 16); q += __shfl_xor(q, 32);
    if (lq == 0) { atomicAdd(&ssum[col], s); atomicAdd(&ssq[col], q); }
  }
}

// GEMM2 (gather, round-5 rewrite): LDS-free, barrier-free direct-to-register.
//   4 waves/block; wave w owns n-cols [w*32, w*32+32) over all 128 rows.
//   A-fragment gather: lane l of m-frag i reads row (i*16 + l&15), 64B chunk lq
//   -> lanes {r,r+16,r+32,r+48} coalesce into ONE 64B line per row; no LDS, no
//   barrier, per-wave counted vmcnt only. B slices distinct per wave (halves the
//   B line traffic of the LDS version). Double-buffered at 32-channel chunks
//   (10 loads -> 16 MFMAs); indices prefetched 2 k ahead, shfl-distributed.
__global__ __launch_bounds__(256) void gemm2_kernel(
    const bf16* __restrict__ a, const bf16* __restrict__ w2k,
    const int* __restrict__ nbrT, const float* __restrict__ ratio,
    float* __restrict__ out2, float* __restrict__ ssum, float* __restrict__ ssq) {
  int row0 = blockIdx.x * 128;
  int tid = threadIdx.x;
  int lane = tid & 63, w = tid >> 6;
  int lr = lane & 15, lq = lane >> 4;
  int rowA = row0 + lane;       if (rowA >= NPTS) rowA = NPTS - 1;
  int rowB = row0 + 64 + lane;  if (rowB >= NPTS) rowB = NPTS - 1;

  f32x4 acc[8][2];
#pragma unroll
  for (int i = 0; i < 8; ++i)
#pragma unroll
    for (int j = 0; j < 2; ++j)
#pragma unroll
      for (int r = 0; r < 4; ++r) acc[i][j][r] = 0.f;

#define LDC(AB, BB, KK, ABP, B0P, B1P) do {                                     \
    _Pragma("unroll")                                                           \
    for (int _i = 0; _i < 8; ++_i)                                              \
      AB[_i] = *(const bf16x8*)(ABP[_i] + (KK) * 32);                           \
    BB[0] = *(const bf16x8*)(B0P + (KK) * 32);                                  \
    BB[1] = *(const bf16x8*)(B1P + (KK) * 32);                                  \
  } while (0)

#define MMA(AB, BB) do {                                                        \
    _Pragma("unroll")                                                           \
    for (int _i = 0; _i < 8; ++_i) {                                            \
      acc[_i][0] = __builtin_amdgcn_mfma_f32_16x16x32_bf16(AB[_i], BB[0], acc[_i][0], 0, 0, 0); \
      acc[_i][1] = __builtin_amdgcn_mfma_f32_16x16x32_bf16(AB[_i], BB[1], acc[_i][1], 0, 0, 0); \
    }                                                                           \
  } while (0)

  // k=0 indices -> A base pointers (lane l of i0/i1 holds idx of local row l / 64+l)
  int i0 = nbrT[rowA], i1 = nbrT[rowB];
  const bf16* ab[8];
#pragma unroll
  for (int i = 0; i < 8; ++i) {
    int idx = __shfl((i < 4) ? i0 : i1, (i & 3) * 16 + lr);
    ab[i] = a + (size_t)idx * PCH + lq * 8;
  }
  const bf16* bb0 = w2k + (size_t)(w * 32 + lr) * PCH + lq * 8;
  const bf16* bb1 = bb0 + 16 * PCH;

  bf16x8 A0[8], A1[8], B0[2], B1[2];
  LDC(A0, B0, 0, ab, bb0, bb1);       // chunk 0 of k=0 in flight
  int i0n = nbrT[NPTS + rowA];        // idx for k=1
  int i1n = nbrT[NPTS + rowB];

#pragma unroll 1
  for (int k = 0; k < KNB; ++k) {
    // bases for k+1 (idx regs arrived >=1 full k earlier)
    const bf16* abn[8];
#pragma unroll
    for (int i = 0; i < 8; ++i) {
      int idx = __shfl((i < 4) ? i0n : i1n, (i & 3) * 16 + lr);
      abn[i] = a + (size_t)idx * PCH + lq * 8;
    }
    LDC(A1, B1, 1, ab, bb0, bb1);     // prefetch chunk 1
    int kn2 = (k + 2 < KNB) ? k + 2 : KNB - 1;
    int i0t = nbrT[(size_t)kn2 * NPTS + rowA];
    int i1t = nbrT[(size_t)kn2 * NPTS + rowB];
    MMA(A0, B0);                      // consume chunk 0
    LDC(A0, B0, 2, ab, bb0, bb1);     // prefetch chunk 2
    MMA(A1, B1);                      // consume chunk 1
    LDC(A1, B1, 3, ab, bb0, bb1);     // prefetch chunk 3
    MMA(A0, B0);                      // consume chunk 2
    if (k + 1 < KNB) {
#pragma unroll
      for (int i = 0; i < 8; ++i) ab[i] = abn[i];
      bb0 += PCH * PCH;  bb1 += PCH * PCH;
      i0n = i0t;  i1n = i1t;
      LDC(A0, B0, 0, ab, bb0, bb1);   // prefetch chunk 0 of k+1
    }
    MMA(A1, B1);                      // consume chunk 3
  }
#undef LDC
#undef MMA

  // epilogue: ratio scale, store, fused channel stats
  float rs[8][4];
#pragma unroll
  for (int i = 0; i < 8; ++i)
#pragma unroll
    for (int r = 0; r < 4; ++r) {
      int row = row0 + i * 16 + lq * 4 + r;
      rs[i][r] = (row < NPTS) ? ratio[row] : 0.f;
    }
#pragma unroll
  for (int j = 0; j < 2; ++j) {
    int col = w * 32 + j * 16 + lr;
    float s = 0.f, q = 0.f;
#pragma unroll
    for (int i = 0; i < 8; ++i) {
#pragma unroll
      for (int r = 0; r < 4; ++r) {
        int row = row0 + i * 16 + lq * 4 + r;
        if (row < NPTS) {
          float v = acc[i][j][r] * rs[i][r];
          out2[(size_t)row * PCH + col] = v;
          s += v; q += v * v;
        }
      }
    }
    s += __shfl_xor(s, 16); s += __shfl_xor(s, 32);
    q += __shfl_xor(q, 16); q += __shfl_xor(q, 32);
    if (lq == 0) { atomicAdd(&ssum[col], s); atomicAdd(&ssq[col], q); }
  }
}

// GEMM3: out3n[n][d] = (bf16)(out2n[n][:] @ W3[:, d]); fused stats (fp32)
__global__ __launch_bounds__(256) void gemm3_kernel(
    const bf16* __restrict__ a, const bf16* __restrict__ w3t, bf16* __restrict__ out3n,
    float* __restrict__ ssum, float* __restrict__ ssq) {
  __shared__ __align__(16) bf16 As[128 * 128];
  int row0 = blockIdx.x * 128;
  int ncol0 = blockIdx.y * 128;
  int tid = threadIdx.x;
  int lane = tid & 63, wid = tid >> 6;
  int mq = (wid >> 1) * 64, nq = (wid & 1) * 64;
  int lr = lane & 15, lq = lane >> 4;
  int rb = tid >> 4;
  int msw = (tid & 15) ^ (rb & 7);
#pragma unroll
  for (int j = 0; j < 8; ++j) {
    int rr = row0 + rb + 16 * j;
    int rc = rr < NPTS ? rr : NPTS - 1;
    gl_lds16(a + (size_t)rc * PCH + (msw << 3),
             &As[(j * 256 + wid * 64) * 8]);
  }
  const bf16* bp = w3t + (size_t)(ncol0 + nq + lr) * PCH + lq * 8;
  bf16x8 bfg[4][4];
#pragma unroll
  for (int c0i = 0; c0i < 4; ++c0i)
#pragma unroll
    for (int i = 0; i < 4; ++i)
      bfg[c0i][i] = *(const bf16x8*)(bp + (size_t)i * 16 * PCH + c0i * 32);
  f32x4 acc[4][4];
#pragma unroll
  for (int i = 0; i < 4; ++i)
#pragma unroll
    for (int j = 0; j < 4; ++j)
#pragma unroll
      for (int r = 0; r < 4; ++r) acc[i][j][r] = 0.f;
  __syncthreads();
#pragma unroll
  for (int c0i = 0; c0i < 4; ++c0i) {
    int cs = ((c0i << 2) + lq) ^ (lr & 7);
    bf16x8 af[4];
#pragma unroll
    for (int i = 0; i < 4; ++i) af[i] = *(const bf16x8*)&As[(mq + i * 16 + lr) * 128 + cs * 8];
#pragma unroll
    for (int i = 0; i < 4; ++i)
#pragma unroll
      for (int j = 0; j < 4; ++j)
        acc[i][j] = __builtin_amdgcn_mfma_f32_16x16x32_bf16(af[i], bfg[c0i][j], acc[i][j], 0, 0, 0);
  }
#pragma unroll
  for (int j = 0; j < 4; ++j) {
    int col = ncol0 + nq + j * 16 + lr;
    float s = 0.f, q = 0.f;
#pragma unroll
    for (int i = 0; i < 4; ++i) {
#pragma unroll
      for (int r = 0; r < 4; ++r) {
        int row = row0 + mq + i * 16 + lq * 4 + r;
        if (row < NPTS) {
          float v = acc[i][j][r];
          out3n[(size_t)row * CIN + col] = (bf16)v;
          s += v; q += v * v;
        }
      }
    }
    s += __shfl_xor(s, 16); s += __shfl_xor(s, 32);
    q += __shfl_xor(q, 16); q += __shfl_xor(q, 32);
    if (lq == 0) { atomicAdd(&ssum[col], s); atomicAdd(&ssq[col], q); }
  }
}

// =================== launch ===================
extern "C" void kernel_launch(void* const* d_in, const int* in_sizes, int n_in,
                              void* d_out, int out_size, void* d_ws, size_t ws_size,
                              hipStream_t stream) {
  const float* x    = (const float*)d_in[0];
  const float* mask = (const float*)d_in[1];
  const int*   nbr  = (const int*)d_in[2];
  const float* W1   = (const float*)d_in[3];
  const float* W2   = (const float*)d_in[4];
  const float* W3   = (const float*)d_in[5];
  float* out = (float*)d_out;
  char* ws = (char*)d_ws;

  auto al = [](size_t x_) { return (x_ + 255) & ~(size_t)255; };
  size_t off = 0;
  size_t OFF_OUT1  = off; off += al((size_t)NPTS * PCH * 4);   // fp32; also out3n lower half
  size_t OFF_OUT2  = off; off += al((size_t)NPTS * PCH * 4);   // fp32; also out3n upper half; xb start
  size_t OFF_OUT1N = off; off += al((size_t)NPTS * PCH * 2);   // xb middle (dead when written)
  size_t OFF_OUT2N = off; off += al((size_t)NPTS * PCH * 2);   // xb end (dead when written)
  size_t OFF_W1T   = off; off += al((size_t)PCH * CIN * 2);
  size_t OFF_W2K   = off; off += al((size_t)KNB * PCH * PCH * 2);
  size_t OFF_W3T   = off; off += al((size_t)CIN * PCH * 2);
  size_t OFF_NBRT  = off; off += al((size_t)KNB * NPTS * 4);
  size_t OFF_RATIO = off; off += al((size_t)NPTS * 4);
  size_t OFF_VAL2  = off; off += al((size_t)NPTS * 4);
  size_t OFF_SUMS  = off; off += al((size_t)1536 * 4);
  size_t OFF_PRMS  = off; off += al((size_t)1536 * 4);

  float* out1   = (float*)(ws + OFF_OUT1);
  float* out2   = (float*)(ws + OFF_OUT2);
  bf16*  out3n  = (bf16*)(ws + OFF_OUT1);   // overlaps out1+out2 (both dead by gemm3)
  bf16*  xb     = (bf16*)(ws + OFF_OUT2);   // 51.2MB over out2+out1n+out2n (all dead until after gemm1)
  bf16*  out1n  = (bf16*)(ws + OFF_OUT1N);
  bf16*  out2n  = (bf16*)(ws + OFF_OUT2N);
  bf16*  w1t    = (bf16*)(ws + OFF_W1T);
  bf16*  w2k    = (bf16*)(ws + OFF_W2K);
  bf16*  w3t    = (bf16*)(ws + OFF_W3T);
  int*   nbrT   = (int*)(ws + OFF_NBRT);
  float* ratio  = (float*)(ws + OFF_RATIO);
  float* valid2 = (float*)(ws + OFF_VAL2);
  float* sums   = (float*)(ws + OFF_SUMS);
  float* s1sum = sums, *s1sq = sums + 128;
  float* s2sum = sums + 256, *s2sq = sums + 384;
  float* s3sum = sums + 512, *s3sq = sums + 1024;
  float* prms = (float*)(ws + OFF_PRMS);
  float* mu1 = prms, *inv1 = prms + 128;
  float* mu2 = prms + 256, *inv2 = prms + 384;
  float* mu3 = prms + 512, *inv3 = prms + 1024;

  hipMemsetAsync(sums, 0, 1536 * 4, stream);

  prep_kernel<<<(NPTS + 255) / 256, 256, 0, stream>>>(nbr, mask, nbrT, ratio, valid2);
  tcvt_kernel<<<(CIN * PCH + 255) / 256, 256, 0, stream>>>(W1, w1t, CIN, PCH);
  tcvt_w2k_kernel<<<(KNB * PCH * PCH + 255) / 256, 256, 0, stream>>>(W2, w2k);
  tcvt_kernel<<<(PCH * CIN + 255) / 256, 256, 0, stream>>>(W3, w3t, PCH, CIN);
  xcvt_kernel<<<(NPTS * CIN / 8 + 255) / 256, 256, 0, stream>>>(x, xb);

  int mblocks = (NPTS + 127) / 128;  // 391

  gemm1_kernel<<<mblocks, 256, 0, stream>>>(xb, w1t, mask, out1, s1sum, s1sq);
  finalize_kernel<<<1, 128, 0, stream>>>(s1sum, s1sq, mu1, inv1);
  ew_kernel<<<(NPTS * PCH / 4 + 255) / 256, 256, 0, stream>>>(out1, mu1, inv1, mask, out1n);

  gemm2_kernel<<<mblocks, 256, 0, stream>>>(out1n, w2k, nbrT, ratio, out2, s2sum, s2sq);
  finalize_kernel<<<1, 128, 0, stream>>>(s2sum, s2sq, mu2, inv2);
  ew_kernel<<<(NPTS * PCH / 4 + 255) / 256, 256, 0, stream>>>(out2, mu2, inv2, valid2, out2n);

  dim3 g3(mblocks, 4);
  gemm3_kernel<<<g3, 256, 0, stream>>>(out2n, w3t, out3n, s3sum, s3sq);
  finalize_kernel<<<1, 512, 0, stream>>>(s3sum, s3sq, mu3, inv3);
  final_kernel<<<(NPTS * CIN / 8 + 255) / 256, 256, 0, stream>>>(x, out3n, mu3, inv3, out);
  maskout_kernel<<<(NPTS + 255) / 256, 256, 0, stream>>>(mask, valid2, out + (size_t)NPTS * CIN);
}

// Round 6
// 624.913 us; speedup vs baseline: 1.0561x; 1.0561x over previous
//
#include <hip/hip_runtime.h>
#include <hip/hip_bf16.h>

#define NPTS 50000
#define CIN  512
#define PCH  128
#define KNB  27
#define EPSV 1e-5f
#define NEGS 0.1f

typedef __bf16 bf16;
typedef __bf16 bf16x8 __attribute__((ext_vector_type(8)));
typedef __bf16 bf16x4 __attribute__((ext_vector_type(4)));
typedef float  f32x4  __attribute__((ext_vector_type(4)));

// ---- async global->LDS (16B per lane). LDS dest = wave-uniform base + lane*16. ----
typedef void __attribute__((address_space(3)))* as3ptr;
typedef const void __attribute__((address_space(1)))* as1ptr;
__device__ __forceinline__ void gl_lds16(const void* g, void* l) {
  __builtin_amdgcn_global_load_lds((as1ptr)g, (as3ptr)l, 16, 0, 0);
}

// Round-6 geometry: 64-row x 128-col tiles (was 128x128). Grid 782 blocks
// (3.05/CU) doubles resident waves/CU vs 391; LDS dbuf 2x16KB=32KB keeps 4+
// blocks/CU feasible; acc halves to 32 VGPR. Same chunk-XOR swizzled LDS
// (write linear via global_load_lds with pre-swizzled source chunk, read with
// cs = C ^ (row&7)), same B-first VMEM order, same depth-1 prefetch drained at
// the end-of-step barrier -- but now ~3 independent blocks/CU overlap each
// other's stage-drain stalls.

// ---------------- x -> bf16 (for global_load_lds staging in gemm1) ----------------
__global__ void xcvt_kernel(const float* __restrict__ x, bf16* __restrict__ xb) {
  int i = (blockIdx.x * blockDim.x + threadIdx.x) * 8;
  if (i >= NPTS * CIN) return;
  float4 a = *(const float4*)&x[i];
  float4 b = *(const float4*)&x[i + 4];
  bf16x8 o;
  o[0] = (bf16)a.x; o[1] = (bf16)a.y; o[2] = (bf16)a.z; o[3] = (bf16)a.w;
  o[4] = (bf16)b.x; o[5] = (bf16)b.y; o[6] = (bf16)b.z; o[7] = (bf16)b.w;
  *(bf16x8*)&xb[i] = o;
}

// ---------------- generic weight transpose+cvt: dst[C][R] = src[R][C] ----
__global__ void tcvt_kernel(const float* __restrict__ src, bf16* __restrict__ dst,
                            int R, int Ccols) {
  int i = blockIdx.x * blockDim.x + threadIdx.x;
  if (i >= R * Ccols) return;
  int c = i / R, r = i - c * R;
  dst[i] = (bf16)src[(size_t)r * Ccols + c];
}

// ---------------- W2 [k][c][d] -> w2k [k][d][c] (bf16) ----------------
__global__ void tcvt_w2k_kernel(const float* __restrict__ src, bf16* __restrict__ dst) {
  int i = blockIdx.x * blockDim.x + threadIdx.x;
  if (i >= KNB * PCH * PCH) return;
  int k = i >> 14, rem = i & 16383;
  int d = rem >> 7, c = rem & 127;
  dst[i] = (bf16)src[(k << 14) + c * 128 + d];
}

// ---------------- prep: nbrT + coverage ratio + valid2 ----------------
__global__ void prep_kernel(const int* __restrict__ nbr, const float* __restrict__ mask,
                            int* __restrict__ nbrT, float* __restrict__ ratio,
                            float* __restrict__ valid2) {
  int n = blockIdx.x * blockDim.x + threadIdx.x;
  if (n >= NPTS) return;
  float s = 0.f;
#pragma unroll
  for (int k = 0; k < KNB; ++k) {
    int idx = nbr[n * KNB + k];
    nbrT[k * NPTS + n] = idx;
    s += (mask[idx] > 0.f) ? 1.f : 0.f;
  }
  ratio[n]  = s > 0.f ? 27.0f / s : 0.f;
  valid2[n] = s > 0.f ? 1.f : 0.f;
}

__global__ void finalize_kernel(const float* __restrict__ ssum, const float* __restrict__ ssq,
                                float* __restrict__ mu, float* __restrict__ inv) {
  int c = threadIdx.x;
  float m = ssum[c] / (float)NPTS;
  float v = ssq[c] / (float)NPTS - m * m;
  mu[c]  = m;
  inv[c] = rsqrtf(v + EPSV);
}

// ---------------- normalize + lrelu + row-mask -> bf16 (C = 128) ----------------
__global__ void ew_kernel(const float* __restrict__ in, const float* __restrict__ mu,
                          const float* __restrict__ inv, const float* __restrict__ rowmask,
                          bf16* __restrict__ outb) {
  int i = (blockIdx.x * blockDim.x + threadIdx.x) * 4;
  if (i >= NPTS * PCH) return;
  float4 v = *(const float4*)&in[i];
  int c = i & 127;
  int row = i >> 7;
  float mk = rowmask[row];
  float t0 = (v.x - mu[c + 0]) * inv[c + 0];
  float t1 = (v.y - mu[c + 1]) * inv[c + 1];
  float t2 = (v.z - mu[c + 2]) * inv[c + 2];
  float t3 = (v.w - mu[c + 3]) * inv[c + 3];
  t0 = (t0 >= 0.f ? t0 : NEGS * t0) * mk;
  t1 = (t1 >= 0.f ? t1 : NEGS * t1) * mk;
  t2 = (t2 >= 0.f ? t2 : NEGS * t2) * mk;
  t3 = (t3 >= 0.f ? t3 : NEGS * t3) * mk;
  bf16x4 o;
  o[0] = (bf16)t0; o[1] = (bf16)t1; o[2] = (bf16)t2; o[3] = (bf16)t3;
  *(bf16x4*)&outb[i] = o;
}

// ---------------- final: out = lrelu(inorm(out3n) + x), out3n bf16 ----------------
__global__ void final_kernel(const float* __restrict__ x, const bf16* __restrict__ out3n,
                             const float* __restrict__ mu, const float* __restrict__ inv,
                             float* __restrict__ out) {
  int i = (blockIdx.x * blockDim.x + threadIdx.x) * 8;
  if (i >= NPTS * CIN) return;
  bf16x8 v = *(const bf16x8*)&out3n[i];
  float4 x0 = *(const float4*)&x[i];
  float4 x1 = *(const float4*)&x[i + 4];
  int c = i & 511;
  float t[8];
  float xv[8] = {x0.x, x0.y, x0.z, x0.w, x1.x, x1.y, x1.z, x1.w};
#pragma unroll
  for (int q = 0; q < 8; ++q) {
    float u = ((float)v[q] - mu[c + q]) * inv[c + q] + xv[q];
    t[q] = u >= 0.f ? u : NEGS * u;
  }
  float4 o0 = {t[0], t[1], t[2], t[3]}, o1 = {t[4], t[5], t[6], t[7]};
  *(float4*)&out[i] = o0;
  *(float4*)&out[i + 4] = o1;
}

__global__ void maskout_kernel(const float* __restrict__ mask, const float* __restrict__ valid2,
                               float* __restrict__ outm) {
  int n = blockIdx.x * blockDim.x + threadIdx.x;
  if (n >= NPTS) return;
  outm[n] = fminf(valid2[n] + mask[n], 1.f);
}

// =================== GEMM kernels ===================
// MFMA 16x16x32 bf16. A frag: lane holds A[m=lane&15][k=(lane>>4)*8+j].
// B frag: lane holds B^T[n=lane&15][k=(lane>>4)*8+j]. C/D: col=lane&15, row=(lane>>4)*4+reg.
// 64-row tile staging: call j (0..3), thread t: LDS row j*16 + (t>>4), physical
// chunk t&15; source logical chunk (t&15) ^ ((t>>4)&7). Wave layout: wave w has
// mq=(w>>1)*32 rows, nq=(w&1)*64 cols; acc[2][4].

// GEMM1: out1[n][d] = (xb[n][:] @ W1)[d] * (mask[n]>0); 64-row tiles, 4 K-tiles
__global__ __launch_bounds__(256) void gemm1_kernel(
    const bf16* __restrict__ xb, const bf16* __restrict__ w1t,
    const float* __restrict__ mask, float* __restrict__ out1,
    float* __restrict__ ssum, float* __restrict__ ssq) {
  __shared__ __align__(16) bf16 As[2][64 * 128];
  int row0 = blockIdx.x * 64;
  int tid = threadIdx.x;
  int lane = tid & 63, wid = tid >> 6;
  int mq = (wid >> 1) * 32, nq = (wid & 1) * 64;
  int lr = lane & 15, lq = lane >> 4;
  int rb = tid >> 4;
  int msw = (tid & 15) ^ (rb & 7);
  int rowc[4];
#pragma unroll
  for (int j = 0; j < 4; ++j) {
    int rr = row0 + j * 16 + rb;
    rowc[j] = rr < NPTS ? rr : NPTS - 1;  // clamp: garbage rows never stored
  }
  f32x4 acc[2][4];
#pragma unroll
  for (int i = 0; i < 2; ++i)
#pragma unroll
    for (int j = 0; j < 4; ++j)
#pragma unroll
      for (int r = 0; r < 4; ++r) acc[i][j][r] = 0.f;

#pragma unroll
  for (int j = 0; j < 4; ++j)
    gl_lds16(xb + (size_t)rowc[j] * CIN + (msw << 3),
             &As[0][(j * 256 + tid) * 8]);
  __syncthreads();

  for (int kc = 0; kc < 4; ++kc) {
    int cur = kc & 1;
    // B fragments FIRST (oldest in vmcnt FIFO)
    const bf16* bp = w1t + (size_t)(nq + lr) * CIN + kc * 128 + lq * 8;
    bf16x8 bfg[4][4];
#pragma unroll
    for (int c0i = 0; c0i < 4; ++c0i)
#pragma unroll
      for (int i = 0; i < 4; ++i)
        bfg[c0i][i] = *(const bf16x8*)(bp + (size_t)i * 16 * CIN + c0i * 32);
    // depth-1 prefetch of next K-tile (drains at the barrier)
    if (kc < 3) {
#pragma unroll
      for (int j = 0; j < 4; ++j)
        gl_lds16(xb + (size_t)rowc[j] * CIN + (kc + 1) * 128 + (msw << 3),
                 &As[cur ^ 1][(j * 256 + tid) * 8]);
    }
#pragma unroll
    for (int c0i = 0; c0i < 4; ++c0i) {
      int cs = ((c0i << 2) + lq) ^ (lr & 7);
      bf16x8 af[2];
#pragma unroll
      for (int i = 0; i < 2; ++i) af[i] = *(const bf16x8*)&As[cur][(mq + i * 16 + lr) * 128 + cs * 8];
#pragma unroll
      for (int i = 0; i < 2; ++i)
#pragma unroll
        for (int j = 0; j < 4; ++j)
          acc[i][j] = __builtin_amdgcn_mfma_f32_16x16x32_bf16(af[i], bfg[c0i][j], acc[i][j], 0, 0, 0);
    }
    __syncthreads();
  }
  // epilogue: mask scale, store, fused channel stats
  float rs[2][4];
#pragma unroll
  for (int i = 0; i < 2; ++i)
#pragma unroll
    for (int r = 0; r < 4; ++r) {
      int row = row0 + mq + i * 16 + lq * 4 + r;
      rs[i][r] = (row < NPTS) ? (mask[row] > 0.f ? 1.f : 0.f) : 0.f;
    }
#pragma unroll
  for (int j = 0; j < 4; ++j) {
    int col = nq + j * 16 + lr;
    float s = 0.f, q = 0.f;
#pragma unroll
    for (int i = 0; i < 2; ++i) {
#pragma unroll
      for (int r = 0; r < 4; ++r) {
        int row = row0 + mq + i * 16 + lq * 4 + r;
        if (row < NPTS) {
          float v = acc[i][j][r] * rs[i][r];
          out1[(size_t)row * PCH + col] = v;
          s += v; q += v * v;
        }
      }
    }
    s += __shfl_xor(s, 16); s += __shfl_xor(s, 32);
    q += __shfl_xor(q, 16); q += __shfl_xor(q, 32);
    if (lq == 0) { atomicAdd(&ssum[col], s); atomicAdd(&ssq[col], q); }
  }
}

// GEMM2 (gather): out2[n][d] = ratio[n] * sum_{k,c} a[nbr[k][n]][c] * w2k[k][d][c]
// 64-row tiles, 27 neighbor k-steps, B-first VMEM order, depth-1 LDS prefetch.
__global__ __launch_bounds__(256) void gemm2_kernel(
    const bf16* __restrict__ a, const bf16* __restrict__ w2k,
    const int* __restrict__ nbrT, const float* __restrict__ ratio,
    float* __restrict__ out2, float* __restrict__ ssum, float* __restrict__ ssq) {
  __shared__ __align__(16) bf16 As[2][64 * 128];
  int row0 = blockIdx.x * 64;
  int tid = threadIdx.x;
  int lane = tid & 63, wid = tid >> 6;
  int mq = (wid >> 1) * 32, nq = (wid & 1) * 64;
  int lr = lane & 15, lq = lane >> 4;
  int rb = tid >> 4;
  int msw = (tid & 15) ^ (rb & 7);
  int rowc[4];
#pragma unroll
  for (int j = 0; j < 4; ++j) {
    int rr = row0 + j * 16 + rb;
    rowc[j] = rr < NPTS ? rr : NPTS - 1;
  }
  f32x4 acc[2][4];
#pragma unroll
  for (int i = 0; i < 2; ++i)
#pragma unroll
    for (int j = 0; j < 4; ++j)
#pragma unroll
      for (int r = 0; r < 4; ++r) acc[i][j][r] = 0.f;

  int nidx[4];
  // prologue: idx k=0, stage k=0, idx k=1
#pragma unroll
  for (int j = 0; j < 4; ++j) nidx[j] = nbrT[rowc[j]];
#pragma unroll
  for (int j = 0; j < 4; ++j)
    gl_lds16(a + (size_t)nidx[j] * PCH + (msw << 3),
             &As[0][(j * 256 + tid) * 8]);
#pragma unroll
  for (int j = 0; j < 4; ++j) nidx[j] = nbrT[NPTS + rowc[j]];
  __syncthreads();

  for (int k = 0; k < KNB; ++k) {
    int cur = k & 1;
    // (1) B fragments FIRST (oldest): counted waits won't drain the gather
    const bf16* bp = w2k + ((size_t)k << 14) + (nq + lr) * PCH + lq * 8;
    bf16x8 bfg[4][4];
#pragma unroll
    for (int c0i = 0; c0i < 4; ++c0i)
#pragma unroll
      for (int i = 0; i < 4; ++i)
        bfg[c0i][i] = *(const bf16x8*)(bp + (size_t)i * 16 * PCH + c0i * 32);
    // (2) gather prefetch of tile k+1 (drains only at the barrier)
    if (k + 1 < KNB) {
#pragma unroll
      for (int j = 0; j < 4; ++j)
        gl_lds16(a + (size_t)nidx[j] * PCH + (msw << 3),
                 &As[cur ^ 1][(j * 256 + tid) * 8]);
    }
    // (3) index prefetch for k+2
    if (k + 2 < KNB) {
#pragma unroll
      for (int j = 0; j < 4; ++j) nidx[j] = nbrT[(k + 2) * NPTS + rowc[j]];
    }
    // (4) ds_read + MFMA on tile k
#pragma unroll
    for (int c0i = 0; c0i < 4; ++c0i) {
      int cs = ((c0i << 2) + lq) ^ (lr & 7);
      bf16x8 af[2];
#pragma unroll
      for (int i = 0; i < 2; ++i) af[i] = *(const bf16x8*)&As[cur][(mq + i * 16 + lr) * 128 + cs * 8];
#pragma unroll
      for (int i = 0; i < 2; ++i)
#pragma unroll
        for (int j = 0; j < 4; ++j)
          acc[i][j] = __builtin_amdgcn_mfma_f32_16x16x32_bf16(af[i], bfg[c0i][j], acc[i][j], 0, 0, 0);
    }
    __syncthreads();
  }
  float rs[2][4];
#pragma unroll
  for (int i = 0; i < 2; ++i)
#pragma unroll
    for (int r = 0; r < 4; ++r) {
      int row = row0 + mq + i * 16 + lq * 4 + r;
      rs[i][r] = (row < NPTS) ? ratio[row] : 0.f;
    }
#pragma unroll
  for (int j = 0; j < 4; ++j) {
    int col = nq + j * 16 + lr;
    float s = 0.f, q = 0.f;
#pragma unroll
    for (int i = 0; i < 2; ++i) {
#pragma unroll
      for (int r = 0; r < 4; ++r) {
        int row = row0 + mq + i * 16 + lq * 4 + r;
        if (row < NPTS) {
          float v = acc[i][j][r] * rs[i][r];
          out2[(size_t)row * PCH + col] = v;
          s += v; q += v * v;
        }
      }
    }
    s += __shfl_xor(s, 16); s += __shfl_xor(s, 32);
    q += __shfl_xor(q, 16); q += __shfl_xor(q, 32);
    if (lq == 0) { atomicAdd(&ssum[col], s); atomicAdd(&ssq[col], q); }
  }
}

// GEMM3: out3n[n][d] = (bf16)(out2n[n][:] @ W3[:, d]); fused stats (fp32)
__global__ __launch_bounds__(256) void gemm3_kernel(
    const bf16* __restrict__ a, const bf16* __restrict__ w3t, bf16* __restrict__ out3n,
    float* __restrict__ ssum, float* __restrict__ ssq) {
  __shared__ __align__(16) bf16 As[128 * 128];
  int row0 = blockIdx.x * 128;
  int ncol0 = blockIdx.y * 128;
  int tid = threadIdx.x;
  int lane = tid & 63, wid = tid >> 6;
  int mq = (wid >> 1) * 64, nq = (wid & 1) * 64;
  int lr = lane & 15, lq = lane >> 4;
  int rb = tid >> 4;
  int msw = (tid & 15) ^ (rb & 7);
#pragma unroll
  for (int j = 0; j < 8; ++j) {
    int rr = row0 + rb + 16 * j;
    int rc = rr < NPTS ? rr : NPTS - 1;
    gl_lds16(a + (size_t)rc * PCH + (msw << 3),
             &As[(j * 256 + wid * 64) * 8]);
  }
  const bf16* bp = w3t + (size_t)(ncol0 + nq + lr) * PCH + lq * 8;
  bf16x8 bfg[4][4];
#pragma unroll
  for (int c0i = 0; c0i < 4; ++c0i)
#pragma unroll
    for (int i = 0; i < 4; ++i)
      bfg[c0i][i] = *(const bf16x8*)(bp + (size_t)i * 16 * PCH + c0i * 32);
  f32x4 acc[4][4];
#pragma unroll
  for (int i = 0; i < 4; ++i)
#pragma unroll
    for (int j = 0; j < 4; ++j)
#pragma unroll
      for (int r = 0; r < 4; ++r) acc[i][j][r] = 0.f;
  __syncthreads();
#pragma unroll
  for (int c0i = 0; c0i < 4; ++c0i) {
    int cs = ((c0i << 2) + lq) ^ (lr & 7);
    bf16x8 af[4];
#pragma unroll
    for (int i = 0; i < 4; ++i) af[i] = *(const bf16x8*)&As[(mq + i * 16 + lr) * 128 + cs * 8];
#pragma unroll
    for (int i = 0; i < 4; ++i)
#pragma unroll
      for (int j = 0; j < 4; ++j)
        acc[i][j] = __builtin_amdgcn_mfma_f32_16x16x32_bf16(af[i], bfg[c0i][j], acc[i][j], 0, 0, 0);
  }
#pragma unroll
  for (int j = 0; j < 4; ++j) {
    int col = ncol0 + nq + j * 16 + lr;
    float s = 0.f, q = 0.f;
#pragma unroll
    for (int i = 0; i < 4; ++i) {
#pragma unroll
      for (int r = 0; r < 4; ++r) {
        int row = row0 + mq + i * 16 + lq * 4 + r;
        if (row < NPTS) {
          float v = acc[i][j][r];
          out3n[(size_t)row * CIN + col] = (bf16)v;
          s += v; q += v * v;
        }
      }
    }
    s += __shfl_xor(s, 16); s += __shfl_xor(s, 32);
    q += __shfl_xor(q, 16); q += __shfl_xor(q, 32);
    if (lq == 0) { atomicAdd(&ssum[col], s); atomicAdd(&ssq[col], q); }
  }
}

// =================== launch ===================
extern "C" void kernel_launch(void* const* d_in, const int* in_sizes, int n_in,
                              void* d_out, int out_size, void* d_ws, size_t ws_size,
                              hipStream_t stream) {
  const float* x    = (const float*)d_in[0];
  const float* mask = (const float*)d_in[1];
  const int*   nbr  = (const int*)d_in[2];
  const float* W1   = (const float*)d_in[3];
  const float* W2   = (const float*)d_in[4];
  const float* W3   = (const float*)d_in[5];
  float* out = (float*)d_out;
  char* ws = (char*)d_ws;

  auto al = [](size_t x_) { return (x_ + 255) & ~(size_t)255; };
  size_t off = 0;
  size_t OFF_OUT1  = off; off += al((size_t)NPTS * PCH * 4);   // fp32; also out3n lower half
  size_t OFF_OUT2  = off; off += al((size_t)NPTS * PCH * 4);   // fp32; also out3n upper half; xb start
  size_t OFF_OUT1N = off; off += al((size_t)NPTS * PCH * 2);   // xb middle (dead when written)
  size_t OFF_OUT2N = off; off += al((size_t)NPTS * PCH * 2);   // xb end (dead when written)
  size_t OFF_W1T   = off; off += al((size_t)PCH * CIN * 2);
  size_t OFF_W2K   = off; off += al((size_t)KNB * PCH * PCH * 2);
  size_t OFF_W3T   = off; off += al((size_t)CIN * PCH * 2);
  size_t OFF_NBRT  = off; off += al((size_t)KNB * NPTS * 4);
  size_t OFF_RATIO = off; off += al((size_t)NPTS * 4);
  size_t OFF_VAL2  = off; off += al((size_t)NPTS * 4);
  size_t OFF_SUMS  = off; off += al((size_t)1536 * 4);
  size_t OFF_PRMS  = off; off += al((size_t)1536 * 4);

  float* out1   = (float*)(ws + OFF_OUT1);
  float* out2   = (float*)(ws + OFF_OUT2);
  bf16*  out3n  = (bf16*)(ws + OFF_OUT1);   // overlaps out1+out2 (both dead by gemm3)
  bf16*  xb     = (bf16*)(ws + OFF_OUT2);   // 51.2MB over out2+out1n+out2n (all dead until after gemm1)
  bf16*  out1n  = (bf16*)(ws + OFF_OUT1N);
  bf16*  out2n  = (bf16*)(ws + OFF_OUT2N);
  bf16*  w1t    = (bf16*)(ws + OFF_W1T);
  bf16*  w2k    = (bf16*)(ws + OFF_W2K);
  bf16*  w3t    = (bf16*)(ws + OFF_W3T);
  int*   nbrT   = (int*)(ws + OFF_NBRT);
  float* ratio  = (float*)(ws + OFF_RATIO);
  float* valid2 = (float*)(ws + OFF_VAL2);
  float* sums   = (float*)(ws + OFF_SUMS);
  float* s1sum = sums, *s1sq = sums + 128;
  float* s2sum = sums + 256, *s2sq = sums + 384;
  float* s3sum = sums + 512, *s3sq = sums + 1024;
  float* prms = (float*)(ws + OFF_PRMS);
  float* mu1 = prms, *inv1 = prms + 128;
  float* mu2 = prms + 256, *inv2 = prms + 384;
  float* mu3 = prms + 512, *inv3 = prms + 1024;

  hipMemsetAsync(sums, 0, 1536 * 4, stream);

  prep_kernel<<<(NPTS + 255) / 256, 256, 0, stream>>>(nbr, mask, nbrT, ratio, valid2);
  tcvt_kernel<<<(CIN * PCH + 255) / 256, 256, 0, stream>>>(W1, w1t, CIN, PCH);
  tcvt_w2k_kernel<<<(KNB * PCH * PCH + 255) / 256, 256, 0, stream>>>(W2, w2k);
  tcvt_kernel<<<(PCH * CIN + 255) / 256, 256, 0, stream>>>(W3, w3t, PCH, CIN);
  xcvt_kernel<<<(NPTS * CIN / 8 + 255) / 256, 256, 0, stream>>>(x, xb);

  int mb64 = (NPTS + 63) / 64;       // 782
  int mblocks = (NPTS + 127) / 128;  // 391 (gemm3)

  gemm1_kernel<<<mb64, 256, 0, stream>>>(xb, w1t, mask, out1, s1sum, s1sq);
  finalize_kernel<<<1, 128, 0, stream>>>(s1sum, s1sq, mu1, inv1);
  ew_kernel<<<(NPTS * PCH / 4 + 255) / 256, 256, 0, stream>>>(out1, mu1, inv1, mask, out1n);

  gemm2_kernel<<<mb64, 256, 0, stream>>>(out1n, w2k, nbrT, ratio, out2, s2sum, s2sq);
  finalize_kernel<<<1, 128, 0, stream>>>(s2sum, s2sq, mu2, inv2);
  ew_kernel<<<(NPTS * PCH / 4 + 255) / 256, 256, 0, stream>>>(out2, mu2, inv2, valid2, out2n);

  dim3 g3(mblocks, 4);
  gemm3_kernel<<<g3, 256, 0, stream>>>(out2n, w3t, out3n, s3sum, s3sq);
  finalize_kernel<<<1, 512, 0, stream>>>(s3sum, s3sq, mu3, inv3);
  final_kernel<<<(NPTS * CIN / 8 + 255) / 256, 256, 0, stream>>>(x, out3n, mu3, inv3, out);
  maskout_kernel<<<(NPTS + 255) / 256, 256, 0, stream>>>(mask, valid2, out + (size_t)NPTS * CIN);
}

// Round 7
// 423.160 us; speedup vs baseline: 1.5596x; 1.4768x over previous
//
#include <hip/hip_runtime.h>
#include <hip/hip_bf16.h>

#define NPTS 50000
#define CIN  512
#define PCH  128
#define KNB  27
#define EPSV 1e-5f
#define NEGS 0.1f

typedef __bf16 bf16;
typedef __bf16 bf16x8 __attribute__((ext_vector_type(8)));
typedef __bf16 bf16x4 __attribute__((ext_vector_type(4)));
typedef float  f32x4  __attribute__((ext_vector_type(4)));

// ---- async global->LDS (16B per lane). LDS dest = wave-uniform base + lane*16. ----
typedef void __attribute__((address_space(3)))* as3ptr;
typedef const void __attribute__((address_space(1)))* as1ptr;
__device__ __forceinline__ void gl_lds16(const void* g, void* l) {
  __builtin_amdgcn_global_load_lds((as1ptr)g, (as3ptr)l, 16, 0, 0);
}

// Round-7: round-2 structure (best measured: gemm2 146us) + 4-way N-split waves.
// Each wave owns a DISTINCT 32-col B slice over all 128 rows -> B cache-request
// volume halves (B was 2x-duplicated in the 2x2 wave grid and every B load is an
// L1 miss since the per-k 32KB slice >= L1). A-frag LDS reads are 4x duplicated
// instead -- LDS bandwidth is not the constraint. Gather path unchanged.
// LDS tile: [128 rows][16 chunks of 16B], chunk-XOR swizzle p = c ^ (r&7);
// writes linear (global_load_lds), source global address pre-swizzled, reads
// use cs = C ^ (r&7) -> conflict-free ds_read_b128.

// ---------------- merged preprocessing (5 kernels -> 1, sectioned) ----------------
__global__ void preproc_kernel(const float* __restrict__ x, const float* __restrict__ mask,
                               const int* __restrict__ nbr,
                               const float* __restrict__ W1, const float* __restrict__ W2,
                               const float* __restrict__ W3,
                               bf16* __restrict__ xb, int* __restrict__ nbrT,
                               float* __restrict__ ratio, float* __restrict__ valid2,
                               bf16* __restrict__ w1t, bf16* __restrict__ w2k,
                               bf16* __restrict__ w3t) {
  int i = blockIdx.x * blockDim.x + threadIdx.x;
  const int NX = NPTS * CIN / 8;
  if (i < NX) {                       // xcvt: x -> bf16
    int e = i * 8;
    float4 a = *(const float4*)&x[e];
    float4 b = *(const float4*)&x[e + 4];
    bf16x8 o;
    o[0] = (bf16)a.x; o[1] = (bf16)a.y; o[2] = (bf16)a.z; o[3] = (bf16)a.w;
    o[4] = (bf16)b.x; o[5] = (bf16)b.y; o[6] = (bf16)b.z; o[7] = (bf16)b.w;
    *(bf16x8*)&xb[e] = o;
    return;
  }
  i -= NX;
  const int NW2 = KNB * PCH * PCH;
  if (i < NW2) {                      // W2 [k][c][d] -> w2k [k][d][c]
    int k = i >> 14, rem = i & 16383;
    int d = rem >> 7, c = rem & 127;
    w2k[i] = (bf16)W2[(k << 14) + c * 128 + d];
    return;
  }
  i -= NW2;
  const int NW1 = CIN * PCH;
  if (i < NW1) {                      // W1 [CIN][PCH] -> w1t [PCH][CIN]
    int c = i / CIN, r = i - c * CIN;
    w1t[i] = (bf16)W1[r * PCH + c];
    return;
  }
  i -= NW1;
  const int NW3 = PCH * CIN;
  if (i < NW3) {                      // W3 [PCH][CIN] -> w3t [CIN][PCH]
    int c = i / PCH, r = i - c * PCH;
    w3t[i] = (bf16)W3[r * CIN + c];
    return;
  }
  i -= NW3;
  if (i < NPTS) {                     // prep: nbrT + ratio + valid2
    int n = i;
    float s = 0.f;
#pragma unroll
    for (int k = 0; k < KNB; ++k) {
      int idx = nbr[n * KNB + k];
      nbrT[k * NPTS + n] = idx;
      s += (mask[idx] > 0.f) ? 1.f : 0.f;
    }
    ratio[n]  = s > 0.f ? 27.0f / s : 0.f;
    valid2[n] = s > 0.f ? 1.f : 0.f;
  }
}

__global__ void finalize_kernel(const float* __restrict__ ssum, const float* __restrict__ ssq,
                                float* __restrict__ mu, float* __restrict__ inv) {
  int c = threadIdx.x;
  float m = ssum[c] / (float)NPTS;
  float v = ssq[c] / (float)NPTS - m * m;
  mu[c]  = m;
  inv[c] = rsqrtf(v + EPSV);
}

// ---------------- normalize + lrelu + row-mask -> bf16 (C = 128) ----------------
__global__ void ew_kernel(const float* __restrict__ in, const float* __restrict__ mu,
                          const float* __restrict__ inv, const float* __restrict__ rowmask,
                          bf16* __restrict__ outb) {
  int i = (blockIdx.x * blockDim.x + threadIdx.x) * 4;
  if (i >= NPTS * PCH) return;
  float4 v = *(const float4*)&in[i];
  int c = i & 127;
  int row = i >> 7;
  float mk = rowmask[row];
  float t0 = (v.x - mu[c + 0]) * inv[c + 0];
  float t1 = (v.y - mu[c + 1]) * inv[c + 1];
  float t2 = (v.z - mu[c + 2]) * inv[c + 2];
  float t3 = (v.w - mu[c + 3]) * inv[c + 3];
  t0 = (t0 >= 0.f ? t0 : NEGS * t0) * mk;
  t1 = (t1 >= 0.f ? t1 : NEGS * t1) * mk;
  t2 = (t2 >= 0.f ? t2 : NEGS * t2) * mk;
  t3 = (t3 >= 0.f ? t3 : NEGS * t3) * mk;
  bf16x4 o;
  o[0] = (bf16)t0; o[1] = (bf16)t1; o[2] = (bf16)t2; o[3] = (bf16)t3;
  *(bf16x4*)&outb[i] = o;
}

// ---------------- final: out = lrelu(inorm(out3n) + x); + fused maskout ----------------
__global__ void final_kernel(const float* __restrict__ x, const bf16* __restrict__ out3n,
                             const float* __restrict__ mu, const float* __restrict__ inv,
                             const float* __restrict__ mask, const float* __restrict__ valid2,
                             float* __restrict__ out) {
  int gid = blockIdx.x * blockDim.x + threadIdx.x;
  if (gid < NPTS) {
    out[(size_t)NPTS * CIN + gid] = fminf(valid2[gid] + mask[gid], 1.f);
  }
  int i = gid * 8;
  if (i >= NPTS * CIN) return;
  bf16x8 v = *(const bf16x8*)&out3n[i];
  float4 x0 = *(const float4*)&x[i];
  float4 x1 = *(const float4*)&x[i + 4];
  int c = i & 511;
  float t[8];
  float xv[8] = {x0.x, x0.y, x0.z, x0.w, x1.x, x1.y, x1.z, x1.w};
#pragma unroll
  for (int q = 0; q < 8; ++q) {
    float u = ((float)v[q] - mu[c + q]) * inv[c + q] + xv[q];
    t[q] = u >= 0.f ? u : NEGS * u;
  }
  float4 o0 = {t[0], t[1], t[2], t[3]}, o1 = {t[4], t[5], t[6], t[7]};
  *(float4*)&out[i] = o0;
  *(float4*)&out[i + 4] = o1;
}

// =================== GEMM kernels ===================
// MFMA 16x16x32 bf16. A frag: lane holds A[m=lane&15][k=(lane>>4)*8+j].
// B frag: lane holds B^T[n=lane&15][k=(lane>>4)*8+j]. C/D: col=lane&15, row=(lane>>4)*4+reg.
// 4-way N-split: wave w owns cols [w*32, w*32+32) over all 128 rows.

// GEMM1: out1[n][d] = (xb[n][:] @ W1)[d] * (mask[n]>0); 128-row tiles, 4 K-tiles
__global__ __launch_bounds__(256) void gemm1_kernel(
    const bf16* __restrict__ xb, const bf16* __restrict__ w1t,
    const float* __restrict__ mask, float* __restrict__ out1,
    float* __restrict__ ssum, float* __restrict__ ssq) {
  __shared__ __align__(16) bf16 As[2][128 * 128];
  int row0 = blockIdx.x * 128;
  int tid = threadIdx.x;
  int lane = tid & 63, wid = tid >> 6;
  int nq = wid * 32;
  int lr = lane & 15, lq = lane >> 4;
  int rb = tid >> 4;
  int msw = (tid & 15) ^ (rb & 7);
  int rowc[8];
#pragma unroll
  for (int j = 0; j < 8; ++j) {
    int rr = row0 + rb + 16 * j;
    rowc[j] = rr < NPTS ? rr : NPTS - 1;  // clamp: garbage rows never stored
  }
  f32x4 acc[8][2];
#pragma unroll
  for (int i = 0; i < 8; ++i)
#pragma unroll
    for (int j = 0; j < 2; ++j)
#pragma unroll
      for (int r = 0; r < 4; ++r) acc[i][j][r] = 0.f;

#pragma unroll
  for (int j = 0; j < 8; ++j)
    gl_lds16(xb + (size_t)rowc[j] * CIN + (msw << 3),
             &As[0][(j * 256 + wid * 64) * 8]);
  __syncthreads();

  for (int kc = 0; kc < 4; ++kc) {
    int cur = kc & 1;
    if (kc < 3) {
#pragma unroll
      for (int j = 0; j < 8; ++j)
        gl_lds16(xb + (size_t)rowc[j] * CIN + (kc + 1) * 128 + (msw << 3),
                 &As[cur ^ 1][(j * 256 + wid * 64) * 8]);
    }
    const bf16* bp = w1t + (size_t)(nq + lr) * CIN + kc * 128 + lq * 8;
#pragma unroll
    for (int c0i = 0; c0i < 4; ++c0i) {
      int cs = ((c0i << 2) + lq) ^ (lr & 7);
      bf16x8 af[8], bfg[2];
#pragma unroll
      for (int i = 0; i < 8; ++i) af[i] = *(const bf16x8*)&As[cur][(i * 16 + lr) * 128 + cs * 8];
#pragma unroll
      for (int j = 0; j < 2; ++j) bfg[j] = *(const bf16x8*)(bp + (size_t)j * 16 * CIN + c0i * 32);
#pragma unroll
      for (int i = 0; i < 8; ++i)
#pragma unroll
        for (int j = 0; j < 2; ++j)
          acc[i][j] = __builtin_amdgcn_mfma_f32_16x16x32_bf16(af[i], bfg[j], acc[i][j], 0, 0, 0);
    }
    __syncthreads();
  }
  // epilogue: mask scale, store, fused channel stats
  float rs[8][4];
#pragma unroll
  for (int i = 0; i < 8; ++i)
#pragma unroll
    for (int r = 0; r < 4; ++r) {
      int row = row0 + i * 16 + lq * 4 + r;
      rs[i][r] = (row < NPTS) ? (mask[row] > 0.f ? 1.f : 0.f) : 0.f;
    }
#pragma unroll
  for (int j = 0; j < 2; ++j) {
    int col = nq + j * 16 + lr;
    float s = 0.f, q = 0.f;
#pragma unroll
    for (int i = 0; i < 8; ++i) {
#pragma unroll
      for (int r = 0; r < 4; ++r) {
        int row = row0 + i * 16 + lq * 4 + r;
        if (row < NPTS) {
          float v = acc[i][j][r] * rs[i][r];
          out1[(size_t)row * PCH + col] = v;
          s += v; q += v * v;
        }
      }
    }
    s += __shfl_xor(s, 16); s += __shfl_xor(s, 32);
    q += __shfl_xor(q, 16); q += __shfl_xor(q, 32);
    if (lq == 0) { atomicAdd(&ssum[col], s); atomicAdd(&ssq[col], q); }
  }
}

// GEMM2 (gather): out2[n][d] = ratio[n] * sum_{k,c} a[nbr[k][n]][c] * w2k[k][d][c]
// Round-2 pipeline (depth-1 gl_lds prefetch, single barrier/k-step) + 4-way N-split.
__global__ __launch_bounds__(256) void gemm2_kernel(
    const bf16* __restrict__ a, const bf16* __restrict__ w2k,
    const int* __restrict__ nbrT, const float* __restrict__ ratio,
    float* __restrict__ out2, float* __restrict__ ssum, float* __restrict__ ssq) {
  __shared__ __align__(16) bf16 As[2][128 * 128];
  int row0 = blockIdx.x * 128;
  int tid = threadIdx.x;
  int lane = tid & 63, wid = tid >> 6;
  int nq = wid * 32;
  int lr = lane & 15, lq = lane >> 4;
  int rb = tid >> 4;
  int msw = (tid & 15) ^ (rb & 7);
  int rowc[8];
#pragma unroll
  for (int j = 0; j < 8; ++j) {
    int rr = row0 + rb + 16 * j;
    rowc[j] = rr < NPTS ? rr : NPTS - 1;
  }
  f32x4 acc[8][2];
#pragma unroll
  for (int i = 0; i < 8; ++i)
#pragma unroll
    for (int j = 0; j < 2; ++j)
#pragma unroll
      for (int r = 0; r < 4; ++r) acc[i][j][r] = 0.f;

  int nidx[8];
  // prologue: idx k=0, stage k=0, idx k=1
#pragma unroll
  for (int j = 0; j < 8; ++j) nidx[j] = nbrT[rowc[j]];
#pragma unroll
  for (int j = 0; j < 8; ++j)
    gl_lds16(a + (size_t)nidx[j] * PCH + (msw << 3),
             &As[0][(j * 256 + wid * 64) * 8]);
#pragma unroll
  for (int j = 0; j < 8; ++j) nidx[j] = nbrT[NPTS + rowc[j]];
  __syncthreads();

  for (int k = 0; k < KNB; ++k) {
    int cur = k & 1;
    // gather prefetch of tile k+1
    if (k + 1 < KNB) {
#pragma unroll
      for (int j = 0; j < 8; ++j)
        gl_lds16(a + (size_t)nidx[j] * PCH + (msw << 3),
                 &As[cur ^ 1][(j * 256 + wid * 64) * 8]);
    }
    // index prefetch for k+2
    if (k + 2 < KNB) {
#pragma unroll
      for (int j = 0; j < 8; ++j) nidx[j] = nbrT[(k + 2) * NPTS + rowc[j]];
    }
    // ds_read + B loads + MFMA on tile k
    const bf16* bp = w2k + ((size_t)k << 14) + (nq + lr) * PCH + lq * 8;
#pragma unroll
    for (int c0i = 0; c0i < 4; ++c0i) {
      int cs = ((c0i << 2) + lq) ^ (lr & 7);
      bf16x8 af[8], bfg[2];
#pragma unroll
      for (int i = 0; i < 8; ++i) af[i] = *(const bf16x8*)&As[cur][(i * 16 + lr) * 128 + cs * 8];
#pragma unroll
      for (int j = 0; j < 2; ++j) bfg[j] = *(const bf16x8*)(bp + (size_t)j * 16 * PCH + c0i * 32);
#pragma unroll
      for (int i = 0; i < 8; ++i)
#pragma unroll
        for (int j = 0; j < 2; ++j)
          acc[i][j] = __builtin_amdgcn_mfma_f32_16x16x32_bf16(af[i], bfg[j], acc[i][j], 0, 0, 0);
    }
    __syncthreads();
  }
  float rs[8][4];
#pragma unroll
  for (int i = 0; i < 8; ++i)
#pragma unroll
    for (int r = 0; r < 4; ++r) {
      int row = row0 + i * 16 + lq * 4 + r;
      rs[i][r] = (row < NPTS) ? ratio[row] : 0.f;
    }
#pragma unroll
  for (int j = 0; j < 2; ++j) {
    int col = nq + j * 16 + lr;
    float s = 0.f, q = 0.f;
#pragma unroll
    for (int i = 0; i < 8; ++i) {
#pragma unroll
      for (int r = 0; r < 4; ++r) {
        int row = row0 + i * 16 + lq * 4 + r;
        if (row < NPTS) {
          float v = acc[i][j][r] * rs[i][r];
          out2[(size_t)row * PCH + col] = v;
          s += v; q += v * v;
        }
      }
    }
    s += __shfl_xor(s, 16); s += __shfl_xor(s, 32);
    q += __shfl_xor(q, 16); q += __shfl_xor(q, 32);
    if (lq == 0) { atomicAdd(&ssum[col], s); atomicAdd(&ssq[col], q); }
  }
}

// GEMM3: out3n[n][d] = (bf16)(out2n[n][:] @ W3[:, d]); fused stats.
// y-loop inside: one block per 128-row tile, stages out2n ONCE, loops 4 ncol tiles.
__global__ __launch_bounds__(256) void gemm3_kernel(
    const bf16* __restrict__ a, const bf16* __restrict__ w3t, bf16* __restrict__ out3n,
    float* __restrict__ ssum, float* __restrict__ ssq) {
  __shared__ __align__(16) bf16 As[128 * 128];
  int row0 = blockIdx.x * 128;
  int tid = threadIdx.x;
  int lane = tid & 63, wid = tid >> 6;
  int nq = wid * 32;
  int lr = lane & 15, lq = lane >> 4;
  int rb = tid >> 4;
  int msw = (tid & 15) ^ (rb & 7);
#pragma unroll
  for (int j = 0; j < 8; ++j) {
    int rr = row0 + rb + 16 * j;
    int rc = rr < NPTS ? rr : NPTS - 1;
    gl_lds16(a + (size_t)rc * PCH + (msw << 3),
             &As[(j * 256 + wid * 64) * 8]);
  }
  __syncthreads();

  for (int yc = 0; yc < 4; ++yc) {
    int ncol0 = yc * 128;
    const bf16* bp = w3t + (size_t)(ncol0 + nq + lr) * PCH + lq * 8;
    f32x4 acc[8][2];
#pragma unroll
    for (int i = 0; i < 8; ++i)
#pragma unroll
      for (int j = 0; j < 2; ++j)
#pragma unroll
        for (int r = 0; r < 4; ++r) acc[i][j][r] = 0.f;
#pragma unroll
    for (int c0i = 0; c0i < 4; ++c0i) {
      int cs = ((c0i << 2) + lq) ^ (lr & 7);
      bf16x8 af[8], bfg[2];
#pragma unroll
      for (int i = 0; i < 8; ++i) af[i] = *(const bf16x8*)&As[(i * 16 + lr) * 128 + cs * 8];
#pragma unroll
      for (int j = 0; j < 2; ++j) bfg[j] = *(const bf16x8*)(bp + (size_t)j * 16 * PCH + c0i * 32);
#pragma unroll
      for (int i = 0; i < 8; ++i)
#pragma unroll
        for (int j = 0; j < 2; ++j)
          acc[i][j] = __builtin_amdgcn_mfma_f32_16x16x32_bf16(af[i], bfg[j], acc[i][j], 0, 0, 0);
    }
#pragma unroll
    for (int j = 0; j < 2; ++j) {
      int col = ncol0 + nq + j * 16 + lr;
      float s = 0.f, q = 0.f;
#pragma unroll
      for (int i = 0; i < 8; ++i) {
#pragma unroll
        for (int r = 0; r < 4; ++r) {
          int row = row0 + i * 16 + lq * 4 + r;
          if (row < NPTS) {
            float v = acc[i][j][r];
            out3n[(size_t)row * CIN + col] = (bf16)v;
            s += v; q += v * v;
          }
        }
      }
      s += __shfl_xor(s, 16); s += __shfl_xor(s, 32);
      q += __shfl_xor(q, 16); q += __shfl_xor(q, 32);
      if (lq == 0) { atomicAdd(&ssum[col], s); atomicAdd(&ssq[col], q); }
    }
  }
}

// =================== launch ===================
extern "C" void kernel_launch(void* const* d_in, const int* in_sizes, int n_in,
                              void* d_out, int out_size, void* d_ws, size_t ws_size,
                              hipStream_t stream) {
  const float* x    = (const float*)d_in[0];
  const float* mask = (const float*)d_in[1];
  const int*   nbr  = (const int*)d_in[2];
  const float* W1   = (const float*)d_in[3];
  const float* W2   = (const float*)d_in[4];
  const float* W3   = (const float*)d_in[5];
  float* out = (float*)d_out;
  char* ws = (char*)d_ws;

  auto al = [](size_t x_) { return (x_ + 255) & ~(size_t)255; };
  size_t off = 0;
  size_t OFF_OUT1  = off; off += al((size_t)NPTS * PCH * 4);   // fp32; also out3n lower half
  size_t OFF_OUT2  = off; off += al((size_t)NPTS * PCH * 4);   // fp32; also out3n upper half; xb start
  size_t OFF_OUT1N = off; off += al((size_t)NPTS * PCH * 2);   // xb middle (dead when written)
  size_t OFF_OUT2N = off; off += al((size_t)NPTS * PCH * 2);   // xb end (dead when written)
  size_t OFF_W1T   = off; off += al((size_t)PCH * CIN * 2);
  size_t OFF_W2K   = off; off += al((size_t)KNB * PCH * PCH * 2);
  size_t OFF_W3T   = off; off += al((size_t)CIN * PCH * 2);
  size_t OFF_NBRT  = off; off += al((size_t)KNB * NPTS * 4);
  size_t OFF_RATIO = off; off += al((size_t)NPTS * 4);
  size_t OFF_VAL2  = off; off += al((size_t)NPTS * 4);
  size_t OFF_SUMS  = off; off += al((size_t)1536 * 4);
  size_t OFF_PRMS  = off; off += al((size_t)1536 * 4);

  float* out1   = (float*)(ws + OFF_OUT1);
  float* out2   = (float*)(ws + OFF_OUT2);
  bf16*  out3n  = (bf16*)(ws + OFF_OUT1);   // overlaps out1+out2 (both dead by gemm3)
  bf16*  xb     = (bf16*)(ws + OFF_OUT2);   // 51.2MB over out2+out1n+out2n (dead until after gemm1)
  bf16*  out1n  = (bf16*)(ws + OFF_OUT1N);
  bf16*  out2n  = (bf16*)(ws + OFF_OUT2N);
  bf16*  w1t    = (bf16*)(ws + OFF_W1T);
  bf16*  w2k    = (bf16*)(ws + OFF_W2K);
  bf16*  w3t    = (bf16*)(ws + OFF_W3T);
  int*   nbrT   = (int*)(ws + OFF_NBRT);
  float* ratio  = (float*)(ws + OFF_RATIO);
  float* valid2 = (float*)(ws + OFF_VAL2);
  float* sums   = (float*)(ws + OFF_SUMS);
  float* s1sum = sums, *s1sq = sums + 128;
  float* s2sum = sums + 256, *s2sq = sums + 384;
  float* s3sum = sums + 512, *s3sq = sums + 1024;
  float* prms = (float*)(ws + OFF_PRMS);
  float* mu1 = prms, *inv1 = prms + 128;
  float* mu2 = prms + 256, *inv2 = prms + 384;
  float* mu3 = prms + 512, *inv3 = prms + 1024;

  hipMemsetAsync(sums, 0, 1536 * 4, stream);

  const int NPRE = NPTS * CIN / 8 + KNB * PCH * PCH + CIN * PCH + PCH * CIN + NPTS;
  preproc_kernel<<<(NPRE + 255) / 256, 256, 0, stream>>>(
      x, mask, nbr, W1, W2, W3, xb, nbrT, ratio, valid2, w1t, w2k, w3t);

  int mblocks = (NPTS + 127) / 128;  // 391

  gemm1_kernel<<<mblocks, 256, 0, stream>>>(xb, w1t, mask, out1, s1sum, s1sq);
  finalize_kernel<<<1, 128, 0, stream>>>(s1sum, s1sq, mu1, inv1);
  ew_kernel<<<(NPTS * PCH / 4 + 255) / 256, 256, 0, stream>>>(out1, mu1, inv1, mask, out1n);

  gemm2_kernel<<<mblocks, 256, 0, stream>>>(out1n, w2k, nbrT, ratio, out2, s2sum, s2sq);
  finalize_kernel<<<1, 128, 0, stream>>>(s2sum, s2sq, mu2, inv2);
  ew_kernel<<<(NPTS * PCH / 4 + 255) / 256, 256, 0, stream>>>(out2, mu2, inv2, valid2, out2n);

  gemm3_kernel<<<mblocks, 256, 0, stream>>>(out2n, w3t, out3n, s3sum, s3sq);
  finalize_kernel<<<1, 512, 0, stream>>>(s3sum, s3sq, mu3, inv3);
  final_kernel<<<(NPTS * CIN / 8 + 255) / 256, 256, 0, stream>>>(
      x, out3n, mu3, inv3, mask, valid2, out);
}